// Round 7
// baseline (65.022 us; speedup 1.0000x reference)
//
#include <hip/hip_runtime.h>

#define WN 128
#define KN 32
#define CN 9
#define NBND 129           // W+1 boundary positions
#define NEGF (-1e30f)
#define CW 8               // transitions per DP/edge chunk
#define NFILL 2048         // zero-fill blocks
#define PIf 3.14159265358979323846f

// NOTE on wrap: reference computes (x + pi) % (2pi) - pi. Here every wrapped
// argument is ps - pe with ps,pe in [0,1), so x in (-1,1), x+pi in (2.1,4.2)
// subset [0,2pi). fmodf(a,2pi) == a exactly on that range (fmod is exact), and
// the sign correction never fires. So wrap(x) == fl(fl(x+pi) - pi): identical
// float op sequence to XLA, no division needed.

// Fused kernel: blocks 0..B-1 = per-batch {chunked LDS-staged edge eval +
// register-resident Viterbi DP with early death exit + in-loop greedy keys +
// backtrack + anchors -> ws staging}. Blocks B.. = zero-fill of the 135MB
// output at full write BW; the DP work hides under it.
__global__ __launch_bounds__(256, 1) void fused_kernel(const float* __restrict__ tok,
                                                       float4* __restrict__ anchors,
                                                       int* __restrict__ meta,
                                                       float4* __restrict__ outz,
                                                       long total4, int B) {
    const int bid = blockIdx.x;
    const int t = threadIdx.x;

    if (bid >= B) {
        long i = (long)(bid - B) * 256 + t;
        const long stride = (long)NFILL * 256;
        float4 z = make_float4(0.f, 0.f, 0.f, 0.f);
        for (; i < total4; i += stride) outz[i] = z;
        return;
    }

    const int b = bid;
    const float* T = tok + (size_t)b * WN * KN * CN;

    __shared__ float sm_tok[(CW + 1) * KN * CN];      // 10368 B token slab
    __shared__ unsigned sm_cmask[CW * KN];            // per-(ci,kn) kp-masks
    __shared__ unsigned sm_cun[CW];                   // per-ci union of masks
    __shared__ signed char sm_prev[WN * KN];          // 4 KB
    __shared__ unsigned long long s_key[KN];          // greedy per-root keys
    __shared__ unsigned char s_path[KN][WN];          // 4 KB
    __shared__ float s_d[KN][NBND];                   // 16.5 KB
    __shared__ int s_we[KN];
    __shared__ int s_e[KN];
    __shared__ int s_alive;
    __shared__ int s_wstop;

    if (t < KN) { s_key[t] = 0ull; s_we[t] = -1; }
    if (t == 0) { s_alive = 1; s_wstop = WN; }

    float best = NEGF;                                // DP carry (wave 0)
    int root = 0;

    for (int c0 = 1; c0 < WN; c0 += CW) {
        const int cend = (c0 + CW < WN) ? (c0 + CW) : WN;
        const int cn = cend - c0;

        // ---- stage windows [c0-1, cend-1] (cn+1 windows), coalesced float4
        {
            const float4* src = (const float4*)(T + (size_t)(c0 - 1) * KN * CN);
            float4* dst = (float4*)sm_tok;
            const int nf4 = (cn + 1) * (KN * CN / 4); // (cn+1)*72
            for (int j = t; j < nf4; j += 256) dst[j] = src[j];
        }
        if (t < CW) sm_cun[t] = 0u;
        __syncthreads();

        // ---- edge eval from LDS: combo m = ci*32 + kn; each wave handles 2
        // combos per round (lane halves), ballot packs the 32 kp bits.
        {
            const int kp = t & 31;
            const int half = (t >> 5) & 1;
            const int wave = t >> 6;
            for (int m2 = wave * 2; m2 < cn * KN; m2 += 8) {
                const int m = m2 + half;
                const int ci = m >> 5;
                const int kn = m & 31;
                const float* Tp = &sm_tok[ci * (KN * CN) + kp * CN];
                const float* Tc = &sm_tok[(ci + 1) * (KN * CN) + kn * CN];
                float fe = Tp[4], fs = Tc[3];
                float fm = (fe + fs) * 0.5f;
                bool ok_f = (fm <= 0.0f) || (fabsf(fe - fs) / (fm > 0.0f ? fm : 1.0f) <= 0.05f);
                float aw = (Tc[7] - Tp[8]) + PIf;     // exact wrap (see note)
                float dphi = aw - PIf;
                bool ok_p = fabsf(dphi) <= 0.5f;
                float ae = Tp[6], an = Tc[5];
                float am = fmaxf(ae, an);
                bool ok_a = (am <= 0.0f) || (fabsf(ae - an) / (am > 0.0f ? am : 1.0f) <= 0.5f);
                bool ok = (Tp[0] > 0.0f) && (Tc[0] > 0.0f) && ok_f && ok_p && ok_a;
                unsigned long long bal = __ballot(ok);
                unsigned lo = (unsigned)bal, hi = (unsigned)(bal >> 32);
                int lw = t & 63;
                if (lw == 0) {
                    sm_cmask[m2] = lo;
                    if (lo) atomicOr(&sm_cun[m2 >> 5], lo);
                } else if (lw == 32) {
                    sm_cmask[m2 + 1] = hi;
                    if (hi) atomicOr(&sm_cun[(m2 + 1) >> 5], hi);
                }
            }
        }
        __syncthreads();

        // ---- DP steps w in [c0, cend) on wave 0; register-resident carry
        if (t < 64) {
            __builtin_amdgcn_s_setprio(1);
            const int kn = t & 31;
            if (c0 == 1) {
                float s0 = sm_tok[kn * CN + 0];       // snr at window 0
                best = (s0 > 0.0f) ? s0 : NEGF;
                root = kn;
            }
            bool died = false;
            for (int w = c0; w < cend; ++w) {
                if (__ballot(best > NEGF) == 0ull) {  // monotone death
                    died = true;
                    if (t == 0) { s_alive = 0; s_wstop = w; }
                    break;
                }
                const int ci = w - c0;
                unsigned mask = sm_cmask[ci * KN + kn];
                float sn = sm_tok[(ci + 1) * (KN * CN) + kn * CN + 0];
                unsigned un = (unsigned)__builtin_amdgcn_readfirstlane((int)sm_cun[ci]);
                float v = NEGF;
                int idx = 0, nr = 0;
                while (un) {                          // sparse: ~few bits
                    int i = __builtin_amdgcn_readfirstlane(__builtin_ctz(un));
                    un &= un - 1u;
                    float bv = __int_as_float(
                        __builtin_amdgcn_readlane(__float_as_int(best), i));
                    int rv = __builtin_amdgcn_readlane(root, i);
                    bool c = ((mask >> i) & 1u) && (bv > v);  // strict > = first-argmax
                    v = c ? bv : v;
                    idx = c ? i : idx;
                    nr = c ? rv : nr;
                }
                bool reached = v > -5e29f;            // bf > NEG*0.5
                float te = v + sn;
                if (t < 32) sm_prev[w * KN + kn] = reached ? (signed char)idx : (signed char)-1;
                if (reached) {
                    root = nr;
                    best = te;
                    if (t < 32) {                     // greedy key (per-root max)
                        unsigned ubk = __float_as_uint(te);
                        ubk ^= (ubk >> 31) ? 0xFFFFFFFFu : 0x80000000u;
                        unsigned e = (unsigned)(w * KN + kn);
                        unsigned long long key = ((unsigned long long)ubk << 32)
                                               | (unsigned long long)(0xFFFFFFFFu - e);
                        atomicMax(&s_key[root], key);
                    }
                } else {
                    best = NEGF;
                }
            }
            if (!died) {                              // chunk-end death check
                if (__ballot(best > NEGF) == 0ull) {
                    if (t == 0) { s_alive = 0; s_wstop = cend; }
                }
            }
            __builtin_amdgcn_s_setprio(0);
        }
        __syncthreads();
        if (!s_alive) break;
    }

    // ---- fill prev = -1 for never-computed steps
    {
        const int wstop = s_wstop;
        for (int i2 = wstop * KN + t; i2 < WN * KN; i2 += 256)
            sm_prev[i2] = (signed char)-1;
    }
    __syncthreads();

    // ---- backtrack selected chain per root (32 lanes in parallel)
    if (t < KN) {
        unsigned long long key = s_key[t];
        int we = -1, e = -1;
        if (key != 0ull) {
            e = (int)(0xFFFFFFFFu - (unsigned)(key & 0xFFFFFFFFull));
            we = e >> 5;
            int k = e & 31;
            for (int ww = we; ww > 0; --ww) {
                s_path[t][ww] = (unsigned char)k;
                k = sm_prev[ww * KN + k];
            }
            s_path[t][0] = (unsigned char)k;
        }
        s_we[t] = we;
        s_e[t] = e;
        meta[b * KN + t] = we;
        meta[(size_t)B * KN + b * KN + t] = e;
    }
    __syncthreads();

    // ---- phase increments d_j + anchor A/t/f into ws staging (all waves;
    // token rows involved are L2-hot from the staging loads)
    for (int u = t; u < KN * NBND; u += 256) {
        int r = u / NBND, bp = u - r * NBND;
        int we = s_we[r];
        if (we < 0) continue;
        if (bp <= we) {
            float dv;
            int pj = s_path[r][bp];
            if (bp == 0) {
                const float* Tq = T + pj * CN;
                dv = Tq[8] - Tq[7];                   // d_first = pe0 - ps0 (ws == 0)
            } else {
                int pm = s_path[r][bp - 1];
                float pe_prev = T[((bp - 1) * KN + pm) * CN + 8];
                float psj = T[(bp * KN + pj) * CN + 7];
                float pej = T[(bp * KN + pj) * CN + 8];
                float aw = (psj - pe_prev) + PIf;     // exact wrap (see note)
                dv = (aw - PIf) + pej - psj;
            }
            s_d[r][bp] = dv;
        }
        int L = we + 1;
        if (bp <= L) {
            float aA, at, af;
            if (bp == 0) {
                const float* Tq = T + (int)s_path[r][0] * CN;
                at = Tq[1]; af = Tq[3]; aA = Tq[5];
            } else if (bp == L) {
                const float* Tq = T + (we * KN + (int)s_path[r][we]) * CN;
                at = Tq[2]; af = Tq[4]; aA = Tq[6];
            } else {
                const float* Ta = T + ((bp - 1) * KN + (int)s_path[r][bp - 1]) * CN;
                const float* Tb = T + (bp * KN + (int)s_path[r][bp]) * CN;
                at = (Ta[2] + Tb[1]) * 0.5f;
                af = (Ta[4] + Tb[3]) * 0.5f;
                aA = (Ta[6] + Tb[5]) * 0.5f;
            }
            float* arow = (float*)(anchors + ((size_t)b * KN + r) * NBND + bp);
            arow[0] = aA; arow[1] = at; arow[3] = af; // [2]=phi below
        }
    }
    __syncthreads();

    // ---- serial phase cumsum per root into staging
    if (t < KN && s_we[t] >= 0) {
        int we = s_we[t];
        int p0 = s_path[t][0];
        float cum = T[p0 * CN + 7];                   // ps0
        float* arow = (float*)(anchors + ((size_t)b * KN + t) * NBND);
        arow[2] = cum;
        for (int j = 0; j <= we; ++j) {
            cum += s_d[t][j];
            arow[(j + 1) * 4 + 2] = cum;
        }
    }
}

// Tiny scatter: copy the <=32 finished anchor rows per batch over the zeros.
__global__ __launch_bounds__(256) void scatter_kernel(const float4* __restrict__ anchors,
                                                      const int* __restrict__ meta,
                                                      float4* __restrict__ out, int B) {
    const int b = blockIdx.x;
    const int t = threadIdx.x;
    for (int u = t; u < KN * NBND; u += 256) {
        int r = u / NBND, bp = u - r * NBND;
        int we = meta[b * KN + r];
        if (we < 0 || bp > we + 1) continue;
        int e = meta[(size_t)B * KN + b * KN + r];
        out[((size_t)b * (WN * KN) + e) * NBND + bp] =
            anchors[((size_t)b * KN + r) * NBND + bp];
    }
}

extern "C" void kernel_launch(void* const* d_in, const int* in_sizes, int n_in,
                              void* d_out, int out_size, void* d_ws, size_t ws_size,
                              hipStream_t stream) {
    const float* tok = (const float*)d_in[0];
    int B = in_sizes[0] / (WN * KN * CN);

    size_t off = 0;
    float4* anchors = (float4*)d_ws;
    off += (size_t)B * KN * NBND * sizeof(float4);
    off = (off + 255) & ~(size_t)255;
    int* meta = (int*)((char*)d_ws + off);

    long total4 = (long)out_size / 4;

    hipLaunchKernelGGL(fused_kernel, dim3(B + NFILL), dim3(256), 0, stream,
                       tok, anchors, meta, (float4*)d_out, total4, B);
    hipLaunchKernelGGL(scatter_kernel, dim3(B), dim3(256), 0, stream,
                       anchors, meta, (float4*)d_out, B);
}

// Round 8
// 53.394 us; speedup vs baseline: 1.2178x; 1.2178x over previous
//
#include <hip/hip_runtime.h>

#define WN 128
#define KN 32
#define CN 9
#define NBND 129           // W+1 boundary positions
#define NEGF (-1e30f)
#define CW 8               // transitions per DP/edge chunk
#define TPB 512            // threads per DP block (8 waves)
#define PIf 3.14159265358979323846f

// NOTE on wrap: reference computes (x + pi) % (2pi) - pi. Every wrapped
// argument here is ps - pe with ps,pe in [0,1), so x in (-1,1), x+pi in
// (2.1,4.2) subset [0,2pi). fmodf(a,2pi) == a exactly on that range (fmod is
// exact) and the sign fix never fires, so wrap(x) == fl(fl(x+pi) - pi):
// identical float sequence to XLA. Validated absmax=0 in rounds 7.

// One block per batch: chunked LDS-staged edge eval + register-resident
// Viterbi DP (early death exit) + in-loop greedy keys + backtrack + anchor
// rows written DIRECTLY over the already-zeroed output.
__global__ __launch_bounds__(TPB) void dp_kernel(const float* __restrict__ tok,
                                                 float* __restrict__ out) {
    const int b = blockIdx.x;
    const int t = threadIdx.x;
    const float* T = tok + (size_t)b * WN * KN * CN;

    __shared__ float sm_tok[(CW + 1) * KN * CN];      // 10368 B token slab
    __shared__ unsigned sm_cmask[CW * KN];            // per-(ci,kn) kp-masks
    __shared__ unsigned sm_cun[CW];                   // per-ci union of masks
    __shared__ signed char sm_prev[WN * KN];          // 4 KB
    __shared__ unsigned long long s_key[KN];          // greedy per-root keys
    __shared__ unsigned char s_path[KN][WN];          // 4 KB
    __shared__ float s_d[KN][NBND];                   // 16.5 KB
    __shared__ int s_we[KN];
    __shared__ int s_e[KN];
    __shared__ int s_alive;
    __shared__ int s_wstop;

    if (t < KN) { s_key[t] = 0ull; s_we[t] = -1; }
    if (t == 0) { s_alive = 1; s_wstop = WN; }

    float best = NEGF;                                // DP carry (wave 0)
    int root = 0;

    for (int c0 = 1; c0 < WN; c0 += CW) {
        const int cend = (c0 + CW < WN) ? (c0 + CW) : WN;
        const int cn = cend - c0;

        // ---- stage windows [c0-1, cend-1] (cn+1 windows), coalesced float4
        {
            const float4* src = (const float4*)(T + (size_t)(c0 - 1) * KN * CN);
            float4* dst = (float4*)sm_tok;
            const int nf4 = (cn + 1) * (KN * CN / 4); // (cn+1)*72
            for (int j = t; j < nf4; j += TPB) dst[j] = src[j];
        }
        if (t < CW) sm_cun[t] = 0u;
        __syncthreads();

        // ---- edge eval from LDS: combo m = ci*32 + kn; each wave handles 2
        // combos per round (lane halves), ballot packs the 32 kp bits.
        {
            const int kp = t & 31;
            const int half = (t >> 5) & 1;
            const int wave = t >> 6;                  // 0..7
            for (int m2 = wave * 2; m2 < cn * KN; m2 += 2 * (TPB / 64)) {
                const int m = m2 + half;
                const int ci = m >> 5;
                const int kn = m & 31;
                const float* Tp = &sm_tok[ci * (KN * CN) + kp * CN];
                const float* Tc = &sm_tok[(ci + 1) * (KN * CN) + kn * CN];
                float fe = Tp[4], fs = Tc[3];
                float fm = (fe + fs) * 0.5f;
                bool ok_f = (fm <= 0.0f) || (fabsf(fe - fs) / (fm > 0.0f ? fm : 1.0f) <= 0.05f);
                float aw = (Tc[7] - Tp[8]) + PIf;     // exact wrap (see note)
                float dphi = aw - PIf;
                bool ok_p = fabsf(dphi) <= 0.5f;
                float ae = Tp[6], an = Tc[5];
                float am = fmaxf(ae, an);
                bool ok_a = (am <= 0.0f) || (fabsf(ae - an) / (am > 0.0f ? am : 1.0f) <= 0.5f);
                bool ok = (Tp[0] > 0.0f) && (Tc[0] > 0.0f) && ok_f && ok_p && ok_a;
                unsigned long long bal = __ballot(ok);
                unsigned lo = (unsigned)bal, hi = (unsigned)(bal >> 32);
                int lw = t & 63;
                if (lw == 0) {
                    sm_cmask[m2] = lo;
                    if (lo) atomicOr(&sm_cun[m2 >> 5], lo);
                } else if (lw == 32) {
                    sm_cmask[m2 + 1] = hi;
                    if (hi) atomicOr(&sm_cun[(m2 + 1) >> 5], hi);
                }
            }
        }
        __syncthreads();

        // ---- DP steps w in [c0, cend) on wave 0; register-resident carry
        if (t < 64) {
            __builtin_amdgcn_s_setprio(1);
            const int kn = t & 31;
            if (c0 == 1) {
                float s0 = sm_tok[kn * CN + 0];       // snr at window 0
                best = (s0 > 0.0f) ? s0 : NEGF;
                root = kn;
            }
            bool died = false;
            for (int w = c0; w < cend; ++w) {
                if (__ballot(best > NEGF) == 0ull) {  // monotone death
                    died = true;
                    if (t == 0) { s_alive = 0; s_wstop = w; }
                    break;
                }
                const int ci = w - c0;
                unsigned mask = sm_cmask[ci * KN + kn];
                float sn = sm_tok[(ci + 1) * (KN * CN) + kn * CN + 0];
                unsigned un = (unsigned)__builtin_amdgcn_readfirstlane((int)sm_cun[ci]);
                float v = NEGF;
                int idx = 0, nr = 0;
                while (un) {                          // sparse: ~few bits
                    int i = __builtin_amdgcn_readfirstlane(__builtin_ctz(un));
                    un &= un - 1u;
                    float bv = __int_as_float(
                        __builtin_amdgcn_readlane(__float_as_int(best), i));
                    int rv = __builtin_amdgcn_readlane(root, i);
                    bool c = ((mask >> i) & 1u) && (bv > v);  // strict > = first-argmax
                    v = c ? bv : v;
                    idx = c ? i : idx;
                    nr = c ? rv : nr;
                }
                bool reached = v > -5e29f;            // bf > NEG*0.5
                float te = v + sn;
                if (t < 32) sm_prev[w * KN + kn] = reached ? (signed char)idx : (signed char)-1;
                if (reached) {
                    root = nr;
                    best = te;
                    if (t < 32) {                     // greedy key (per-root max)
                        unsigned ubk = __float_as_uint(te);
                        ubk ^= (ubk >> 31) ? 0xFFFFFFFFu : 0x80000000u;
                        unsigned e = (unsigned)(w * KN + kn);
                        unsigned long long key = ((unsigned long long)ubk << 32)
                                               | (unsigned long long)(0xFFFFFFFFu - e);
                        atomicMax(&s_key[root], key);
                    }
                } else {
                    best = NEGF;
                }
            }
            if (!died) {                              // chunk-end death check
                if (__ballot(best > NEGF) == 0ull) {
                    if (t == 0) { s_alive = 0; s_wstop = cend; }
                }
            }
            __builtin_amdgcn_s_setprio(0);
        }
        __syncthreads();
        if (!s_alive) break;
    }

    // ---- fill prev = -1 for never-computed steps
    {
        const int wstop = s_wstop;
        for (int i2 = wstop * KN + t; i2 < WN * KN; i2 += TPB)
            sm_prev[i2] = (signed char)-1;
    }
    __syncthreads();

    // ---- backtrack selected chain per root (32 lanes in parallel)
    if (t < KN) {
        unsigned long long key = s_key[t];
        int we = -1, e = -1;
        if (key != 0ull) {
            e = (int)(0xFFFFFFFFu - (unsigned)(key & 0xFFFFFFFFull));
            we = e >> 5;
            int k = e & 31;
            for (int ww = we; ww > 0; --ww) {
                s_path[t][ww] = (unsigned char)k;
                k = sm_prev[ww * KN + k];
            }
            s_path[t][0] = (unsigned char)k;
        }
        s_we[t] = we;
        s_e[t] = e;
    }
    __syncthreads();

    // ---- phase increments d_j + anchor A/t/f DIRECTLY over the zeros
    float* Ob = out + (size_t)b * (WN * KN) * NBND * 4;
    for (int u = t; u < KN * NBND; u += TPB) {
        int r = u / NBND, bp = u - r * NBND;
        int we = s_we[r];
        if (we < 0) continue;
        if (bp <= we) {
            float dv;
            int pj = s_path[r][bp];
            if (bp == 0) {
                const float* Tq = T + pj * CN;
                dv = Tq[8] - Tq[7];                   // d_first = pe0 - ps0 (ws == 0)
            } else {
                int pm = s_path[r][bp - 1];
                float pe_prev = T[((bp - 1) * KN + pm) * CN + 8];
                float psj = T[(bp * KN + pj) * CN + 7];
                float pej = T[(bp * KN + pj) * CN + 8];
                float aw = (psj - pe_prev) + PIf;     // exact wrap (see note)
                dv = (aw - PIf) + pej - psj;
            }
            s_d[r][bp] = dv;
        }
        int L = we + 1;
        if (bp <= L) {
            float aA, at, af;
            if (bp == 0) {
                const float* Tq = T + (int)s_path[r][0] * CN;
                at = Tq[1]; af = Tq[3]; aA = Tq[5];
            } else if (bp == L) {
                const float* Tq = T + (we * KN + (int)s_path[r][we]) * CN;
                at = Tq[2]; af = Tq[4]; aA = Tq[6];
            } else {
                const float* Ta = T + ((bp - 1) * KN + (int)s_path[r][bp - 1]) * CN;
                const float* Tb = T + (bp * KN + (int)s_path[r][bp]) * CN;
                at = (Ta[2] + Tb[1]) * 0.5f;
                af = (Ta[4] + Tb[3]) * 0.5f;
                aA = (Ta[6] + Tb[5]) * 0.5f;
            }
            float* arow = Ob + ((size_t)s_e[r] * NBND + bp) * 4;
            arow[0] = aA; arow[1] = at; arow[3] = af; // [2]=phi below
        }
    }
    __syncthreads();

    // ---- serial phase cumsum per root, direct to out
    if (t < KN && s_we[t] >= 0) {
        int we = s_we[t];
        int p0 = s_path[t][0];
        float cum = T[p0 * CN + 7];                   // ps0
        float* arow = Ob + (size_t)s_e[t] * NBND * 4;
        arow[2] = cum;
        for (int j = 0; j <= we; ++j) {
            cum += s_d[t][j];
            arow[(j + 1) * 4 + 2] = cum;
        }
    }
}

extern "C" void kernel_launch(void* const* d_in, const int* in_sizes, int n_in,
                              void* d_out, int out_size, void* d_ws, size_t ws_size,
                              hipStream_t stream) {
    const float* tok = (const float*)d_in[0];
    int B = in_sizes[0] / (WN * KN * CN);

    // Zero-fill via the runtime's fill path (measured 6.5-6.9 TB/s on this
    // chip, faster than any hand-written fill kernel tried so far), then one
    // self-contained block per batch writes the sparse anchor rows on top.
    hipMemsetAsync(d_out, 0, (size_t)out_size * sizeof(float), stream);
    hipLaunchKernelGGL(dp_kernel, dim3(B), dim3(TPB), 0, stream, tok, (float*)d_out);
}